// Round 9
// baseline (279.842 us; speedup 1.0000x reference)
//
#include <hip/hip_runtime.h>
#include <math.h>

typedef __bf16 bf16x8 __attribute__((ext_vector_type(8)));
typedef __bf16 bf16x4 __attribute__((ext_vector_type(4)));
typedef float f32x4 __attribute__((ext_vector_type(4)));

#define HDIM 128
#define NTHREADS 512

#define EMV 0.001f
#define LFIX 0.05f
#define KFIX 100.0f
#define LAMBDA_L 0.5769230769230769f
#define MU_L 0.3846153846153846f

// swizzled bf16 index: 128-wide rows (activations, W4p), 16B granules blk in [0,16)
__device__ __forceinline__ int swb(int r, int blk) {
    return (r << 7) + ((blk ^ (r & 7)) << 3);
}
// swizzled bf16 index: 32-wide rows (trace weight K-chunk), granules g in [0,4)
__device__ __forceinline__ int swb32(int r, int g) {
    return (r << 5) + ((g ^ ((r >> 1) & 3)) << 3);
}

// tanh = 1 - 2/(e^{2x}+1); rcp form saturates correctly at +/-inf -> no clamp
__device__ __forceinline__ float fast_tanh(float x) {
    float e = __expf(2.f * x);
    return 1.f - 2.f * __builtin_amdgcn_rcpf(e + 1.f);
}

__device__ __forceinline__ float wred(float v) {
#pragma unroll
    for (int off = 32; off > 0; off >>= 1) v += __shfl_down(v, off, 64);
    return v;
}

// 8-wave forward GEMM, col-tile range [CT0,CT1). Wave w owns output rows
// [w*16, w*16+16). out[p][n] = sum_j in[p][j]*W[j][n]; aw[s] = W^T K-step frags.
// Epilogue: buf0 -> tanh(acc+bias) -> outb[0]; bufs 1.. -> acc*(1-h^2).
// In-place safe: reads of rows [CT0*16,CT1*16) precede internal barrier; writes
// touch only those rows. CT width kept <=2 to stay spill-free (round-7 lesson).
template <int NB, int CT0, int CT1>
__device__ __forceinline__ void gemm_f8(const bf16x8 (&aw)[4],
                                        __bf16* const* inb, __bf16* const* outb,
                                        const float* __restrict__ bsL,
                                        int wid, int l15, int q) {
    f32x4 acc[NB][CT1 - CT0];
#pragma unroll
    for (int b = 0; b < NB; ++b)
#pragma unroll
        for (int c = 0; c < CT1 - CT0; ++c) acc[b][c] = (f32x4){0.f, 0.f, 0.f, 0.f};

#pragma unroll
    for (int s = 0; s < 4; ++s)
#pragma unroll
        for (int b = 0; b < NB; ++b)
#pragma unroll
            for (int c = CT0; c < CT1; ++c) {
                bf16x8 bfr = *(const bf16x8*)(inb[b] + swb(c * 16 + l15, s * 4 + q));
                acc[b][c - CT0] = __builtin_amdgcn_mfma_f32_16x16x32_bf16(
                    aw[s], bfr, acc[b][c - CT0], 0, 0, 0);
            }
    __syncthreads();  // all reads done before in-place writes
    const int n0 = wid * 16 + q * 4;
    float4 bv = *(const float4*)(bsL + n0);
    float bias4[4] = {bv.x, bv.y, bv.z, bv.w};
#pragma unroll
    for (int c = CT0; c < CT1; ++c) {
        const int p = c * 16 + l15;
        const int widx = swb(p, n0 >> 3) + (n0 & 7);
        bf16x4 hv;
        float fct[4];
#pragma unroll
        for (int i = 0; i < 4; ++i) {
            float h = fast_tanh(acc[0][c - CT0][i] + bias4[i]);
            hv[i] = (__bf16)h;
            fct[i] = 1.f - h * h;
        }
        *(bf16x4*)(outb[0] + widx) = hv;
#pragma unroll
        for (int b = 1; b < NB; ++b) {
            bf16x4 ov;
#pragma unroll
            for (int i = 0; i < 4; ++i) ov[i] = (__bf16)(acc[b][c - CT0][i] * fct[i]);
            *(bf16x4*)(outb[b] + widx) = ov;
        }
    }
}

// 8-wave trace (VJP) GEMM on a 32-pt tile: out[p][j] = sum_k in[p][k]*W[j][k],
// fct from href, in place. Stages W K-chunks (32-wide) into Wst.
template <int NB>
__device__ __forceinline__ void gemm_tr8(const float* __restrict__ Wg, __bf16* Wst,
                                         __bf16* const* bufs,
                                         const __bf16* __restrict__ href,
                                         int wid, int l15, int q, int tid) {
    f32x4 acc[NB][2];
#pragma unroll
    for (int b = 0; b < NB; ++b) {
        acc[b][0] = (f32x4){0.f, 0.f, 0.f, 0.f};
        acc[b][1] = (f32x4){0.f, 0.f, 0.f, 0.f};
    }
#pragma unroll
    for (int c = 0; c < 4; ++c) {
        __syncthreads();  // previous Wst users done
        {
            int j = tid >> 2, k8 = tid & 3;  // 512 granules of 8
            const float4* src = (const float4*)(Wg + j * HDIM + c * 32 + k8 * 8);
            float4 v0 = src[0], v1 = src[1];
            bf16x8 pk = {(__bf16)v0.x, (__bf16)v0.y, (__bf16)v0.z, (__bf16)v0.w,
                         (__bf16)v1.x, (__bf16)v1.y, (__bf16)v1.z, (__bf16)v1.w};
            *(bf16x8*)(Wst + swb32(j, k8)) = pk;
        }
        __syncthreads();
        bf16x8 afr = *(const bf16x8*)(Wst + swb32(wid * 16 + l15, q));
#pragma unroll
        for (int b = 0; b < NB; ++b) {
            bf16x8 b0 = *(const bf16x8*)(bufs[b] + swb(l15, c * 4 + q));
            acc[b][0] = __builtin_amdgcn_mfma_f32_16x16x32_bf16(afr, b0, acc[b][0], 0, 0, 0);
            bf16x8 b1 = *(const bf16x8*)(bufs[b] + swb(16 + l15, c * 4 + q));
            acc[b][1] = __builtin_amdgcn_mfma_f32_16x16x32_bf16(afr, b1, acc[b][1], 0, 0, 0);
        }
    }
    __syncthreads();  // all reads done before in-place writes
    const int n0 = wid * 16 + q * 4;
#pragma unroll
    for (int ct = 0; ct < 2; ++ct) {
        const int p = ct * 16 + l15;
        const int widx = swb(p, n0 >> 3) + (n0 & 7);
        bf16x4 hv = *(const bf16x4*)(href + widx);
        float fct[4];
#pragma unroll
        for (int i = 0; i < 4; ++i) {
            float h = (float)hv[i];
            fct[i] = 1.f - h * h;
        }
#pragma unroll
        for (int b = 0; b < NB; ++b) {
            bf16x4 ov;
#pragma unroll
            for (int i = 0; i < 4; ++i) ov[i] = (__bf16)(acc[b][ct][i] * fct[i]);
            *(bf16x4*)(bufs[b] + widx) = ov;
        }
    }
}

// 512-thread sum-of-squares of 3 32-pt buffers: npart[(buf*16+cc)*32+p]
__device__ __forceinline__ void dnorms8(const __bf16* a, const __bf16* b, const __bf16* c2,
                                        float* npart, int tid) {
    int p = tid & 31, cc = tid >> 5;  // cc in [0,16)
    bf16x8 v0 = *(const bf16x8*)(a + swb(p, cc));
    bf16x8 v1 = *(const bf16x8*)(b + swb(p, cc));
    bf16x8 v2 = *(const bf16x8*)(c2 + swb(p, cc));
    float s0 = 0.f, s1 = 0.f, s2 = 0.f;
#pragma unroll
    for (int e = 0; e < 8; ++e) {
        float f0 = (float)v0[e], f1 = (float)v1[e], f2 = (float)v2[e];
        s0 += f0 * f0;
        s1 += f1 * f1;
        s2 += f2 * f2;
    }
    npart[(0 + cc) * 32 + p] = s0;
    npart[(16 + cc) * 32 + p] = s1;
    npart[(32 + cc) * 32 + p] = s2;
}

__device__ __forceinline__ float sum16(const float* npart, int buf, int p) {
    float d = 0.f;
#pragma unroll
    for (int i = 0; i < 16; ++i) d += npart[(buf * 16 + i) * 32 + p];
    return d;
}
__device__ __forceinline__ float sum48(const float* npart, int p) {
    float d = 0.f;
#pragma unroll
    for (int i = 0; i < 48; ++i) d += npart[i * 32 + p];
    return d;
}

__global__ void __launch_bounds__(NTHREADS, 4) pinn_all(
    const float* __restrict__ xPhys, const float* __restrict__ coord,
    const float* __restrict__ W1, const float* __restrict__ b1,
    const float* __restrict__ W2, const float* __restrict__ b2,
    const float* __restrict__ W3, const float* __restrict__ b3,
    const float* __restrict__ W4, const float* __restrict__ b4,
    const float* __restrict__ fc, const float* __restrict__ Fv,
    const int* __restrict__ nfixp,
    float* __restrict__ energy_c_out, float* __restrict__ u_out,
    float* __restrict__ acc, int nm32, int nmain64, int ntrb, int NF,
    float* __restrict__ loss_out, int Ntot) {
    // 64KB pool: fwd view = 4 x (64x128) bf16; trace view = 6 x (32x128) + Wstage + npart
    __shared__ __align__(16) __bf16 pool[32768];
    __shared__ __align__(16) __bf16 W4p[16 * HDIM];  // 4KB padded W4^T
    __shared__ __align__(16) float W1s[4 * HDIM];    // w0,w1,w2,b1
    __shared__ __align__(16) float W4ts[3 * HDIM];
    __shared__ __align__(16) float gls[64 * 12];
    __shared__ __align__(16) float uls[64 * 4];
    __shared__ float nh1s[32], nh2s[32], nh3s[32];
    // total ~75.9KB -> 2 blocks/CU, 16 waves/CU

    const int tid = threadIdx.x;
    const int lane = tid & 63, wid = tid >> 6, l15 = lane & 15, q = lane >> 4;
    const int bi = blockIdx.x;
    const int nfixv = nfixp[0];

    // ---- trace-block tile enumeration (same sampled 32-pt sets as verified kernel) ----
    int ttile = -1;
    bool idle = false;
    if (bi < ntrb) {
        const int nfull = nfixv >> 5;          // fully-fix 32-pt tiles
        const int cm = (nfixv & 31) ? 1 : 0;   // mixed tile exists?
        const int c1 = (nfull + 7) >> 3;       // fix trace tiles: t = 8i < nfull
        int t;
        if (bi < c1) {
            t = bi << 3;
        } else if (cm && bi == c1) {
            t = nfull;  // mixed tile always traced
        } else {
            const int rr0 = nfull + cm;
            const int f0 = rr0 + ((8 - (rr0 & 15) + 16) & 15);  // first t>=rr0, t%16==8
            t = f0 + ((bi - c1 - cm) << 4);
        }
        if (t >= nm32) idle = true;  // idle trace block
        else ttile = t;
    }

    if (!idle) {
        // ---- coord prefetch (hides HBM/L2 latency under the staging prologue) ----
        float px0, px1, px2;
        if (bi < ntrb) {
            const float* cp = coord + (ttile * 32 + (lane & 31)) * 3;
            px0 = cp[0]; px1 = cp[1]; px2 = cp[2];
        } else if (bi < ntrb + nmain64) {
            const float* cp = coord + ((bi - ntrb) * 64 + lane) * 3;
            px0 = cp[0]; px1 = cp[1]; px2 = cp[2];
        } else {
            int pp = (bi - ntrb - nmain64) * 64 + lane;
            if (pp >= NF) pp = NF - 1;
            const float* cp = fc + pp * 3;
            px0 = cp[0]; px1 = cp[1]; px2 = cp[2];
        }

        // ---------------- block-invariant staging ----------------
        for (int i = tid; i < 3 * HDIM; i += NTHREADS) W1s[i] = W1[i];
        if (tid < HDIM) W1s[3 * HDIM + tid] = b1[tid];
        if (tid < 3 * HDIM) W4ts[tid] = W4[(tid & 127) * 3 + (tid >> 7)];
        if (tid < 256) {  // W4p (padded W4^T)
            int o = tid >> 4, blk = tid & 15, j0 = blk * 8;
            bf16x8 pk;
#pragma unroll
            for (int e = 0; e < 8; ++e) pk[e] = (__bf16)((o < 3) ? W4[(j0 + e) * 3 + o] : 0.f);
            *(bf16x8*)(W4p + swb(o, blk)) = pk;
        }
        // register-resident W2/W3 fragments: wave w owns n-rows [w*16, w*16+16)
        bf16x8 aw2[4], aw3[4];
#pragma unroll
        for (int s = 0; s < 4; ++s) {
            const int kb = s * 32 + q * 8;
            const int n = wid * 16 + l15;
            bf16x8 v2, v3;
#pragma unroll
            for (int e = 0; e < 8; ++e) {
                v2[e] = (__bf16)W2[(kb + e) * HDIM + n];
                v3[e] = (__bf16)W3[(kb + e) * HDIM + n];
            }
            aw2[s] = v2;
            aw3[s] = v3;
        }
        __syncthreads();

        if (bi < ntrb) {
            // ================= trace block: one sampled 32-pt tile =================
            const int base = ttile * 32;
            __bf16* H1 = pool;
            __bf16* H2 = pool + 4096;
            __bf16* H3 = pool + 8192;
            __bf16* T0 = pool + 12288;
            __bf16* T1 = pool + 16384;
            __bf16* T2 = pool + 20480;
            __bf16* WST = pool + 24576;             // 8KB
            float* npart = (float*)(pool + 28672);  // 1536 floats (6KB)

            {  // layer 1 + tangent seeds: point-per-lane, granule-per-wave
                const int p = lane & 31, sub = lane >> 5;
                const int blk = wid * 2 + sub, j0 = blk * 8;
                bf16x8 hv, t0v, t1v, t2v;
#pragma unroll
                for (int jj = 0; jj < 8; ++jj) {
                    int j = j0 + jj;
                    float w0 = W1s[j], w1 = W1s[HDIM + j], w2 = W1s[2 * HDIM + j];
                    float z = W1s[3 * HDIM + j] + px0 * w0 + px1 * w1 + px2 * w2;
                    float h = fast_tanh(z);
                    float fct = 1.f - h * h;
                    hv[jj] = (__bf16)h;
                    t0v[jj] = (__bf16)(fct * w0);
                    t1v[jj] = (__bf16)(fct * w1);
                    t2v[jj] = (__bf16)(fct * w2);
                }
                int wi = swb(p, blk);
                *(bf16x8*)(H1 + wi) = hv;
                *(bf16x8*)(T0 + wi) = t0v;
                *(bf16x8*)(T1 + wi) = t1v;
                *(bf16x8*)(T2 + wi) = t2v;
            }
            __syncthreads();
            {
                __bf16* ib[4] = {H1, T0, T1, T2};
                __bf16* ob[4] = {H2, T0, T1, T2};
                gemm_f8<4, 0, 2>(aw2, ib, ob, b2, wid, l15, q);
            }
            __syncthreads();
            {
                __bf16* ib[4] = {H2, T0, T1, T2};
                __bf16* ob[4] = {H3, T0, T1, T2};
                gemm_f8<4, 0, 2>(aw3, ib, ob, b3, wid, l15, q);
            }
            __syncthreads();

            dnorms8(H1, H2, H3, npart, tid);
            __syncthreads();
            if (tid < 32) {
                nh1s[tid] = sum16(npart, 0, tid);
                nh2s[tid] = sum16(npart, 1, tid);
                nh3s[tid] = sum16(npart, 2, tid);
            }
            __syncthreads();
            {  // delta3 seeds into T0..T2 (broadcast indexing)
                const int p = lane & 31, sub = lane >> 5;
                const int blk = wid * 2 + sub, j0 = blk * 8;
                bf16x8 h3v = *(const bf16x8*)(H3 + swb(p, blk));
                bf16x8 d0, d1, d2;
#pragma unroll
                for (int e = 0; e < 8; ++e) {
                    float h = (float)h3v[e];
                    float fct = 1.f - h * h;
                    d0[e] = (__bf16)(fct * W4ts[j0 + e]);
                    d1[e] = (__bf16)(fct * W4ts[HDIM + j0 + e]);
                    d2[e] = (__bf16)(fct * W4ts[2 * HDIM + j0 + e]);
                }
                int wi = swb(p, blk);
                *(bf16x8*)(T0 + wi) = d0;
                *(bf16x8*)(T1 + wi) = d1;
                *(bf16x8*)(T2 + wi) = d2;
            }
            __syncthreads();
            float s_acc = 0.f;
            dnorms8(T0, T1, T2, npart, tid);
            __syncthreads();
            if (tid < 32) s_acc = sum48(npart, tid) * (1.f + nh2s[tid]);
            {
                __bf16* ib[3] = {T0, T1, T2};
                gemm_tr8<3>(W3, WST, ib, H2, wid, l15, q, tid);  // delta2
            }
            __syncthreads();
            dnorms8(T0, T1, T2, npart, tid);
            __syncthreads();
            if (tid < 32) s_acc += sum48(npart, tid) * (1.f + nh1s[tid]);
            {
                __bf16* ib[3] = {T0, T1, T2};
                gemm_tr8<3>(W2, WST, ib, H1, wid, l15, q, tid);  // delta1
            }
            __syncthreads();
            dnorms8(T0, T1, T2, npart, tid);
            __syncthreads();
            if (tid < 64) {
                float su = 0.f, sr = 0.f, cu = 0.f, cr = 0.f;
                if (tid < 32) {
                    int p = tid;
                    float nx = px0 * px0 + px1 * px1 + px2 * px2;
                    float s = s_acc + sum48(npart, p) * (1.f + nx) + 3.f * (nh3s[p] + 1.f);
                    bool uu = (base + p) < nfixv;
                    su = uu ? s : 0.f;
                    sr = uu ? 0.f : s;
                    cu = uu ? 1.f : 0.f;
                    cr = uu ? 0.f : 1.f;
                }
                su = wred(su);
                sr = wred(sr);
                cu = wred(cu);
                cr = wred(cr);
                if (tid == 0) {
                    atomicAdd(acc + 3, su);
                    atomicAdd(acc + 4, sr);
                    atomicAdd(acc + 5, cu);
                    atomicAdd(acc + 6, cr);
                }
            }
        } else if (bi < ntrb + nmain64) {
            // ================= forward block: 64 coord points (no trace) =================
            const int base = (bi - ntrb) * 64;
            __bf16* HF = pool;  // in-place h1 -> h2 -> h3
            __bf16* TF0 = pool + 8192;
            __bf16* TF1 = pool + 16384;
            __bf16* TF2 = pool + 24576;

            {  // layer 1 + tangent seeds: point-per-lane, granule-per-wave
                const int p = lane;
#pragma unroll
                for (int it2 = 0; it2 < 2; ++it2) {
                    const int blk = it2 * 8 + wid, j0 = blk * 8;
                    bf16x8 hv, t0v, t1v, t2v;
#pragma unroll
                    for (int jj = 0; jj < 8; ++jj) {
                        int j = j0 + jj;
                        float w0 = W1s[j], w1 = W1s[HDIM + j], w2 = W1s[2 * HDIM + j];
                        float z = W1s[3 * HDIM + j] + px0 * w0 + px1 * w1 + px2 * w2;
                        float h = fast_tanh(z);
                        float fct = 1.f - h * h;
                        hv[jj] = (__bf16)h;
                        t0v[jj] = (__bf16)(fct * w0);
                        t1v[jj] = (__bf16)(fct * w1);
                        t2v[jj] = (__bf16)(fct * w2);
                    }
                    int wi = swb(p, blk);
                    *(bf16x8*)(HF + wi) = hv;
                    *(bf16x8*)(TF0 + wi) = t0v;
                    *(bf16x8*)(TF1 + wi) = t1v;
                    *(bf16x8*)(TF2 + wi) = t2v;
                }
            }
            __syncthreads();
            {  // layer 2 (two col-tile passes, disjoint rows; each has internal barrier)
                __bf16* ib[4] = {HF, TF0, TF1, TF2};
                gemm_f8<4, 0, 2>(aw2, ib, ib, b2, wid, l15, q);
                gemm_f8<4, 2, 4>(aw2, ib, ib, b2, wid, l15, q);
            }
            __syncthreads();
            {  // layer 3
                __bf16* ib[4] = {HF, TF0, TF1, TF2};
                gemm_f8<4, 0, 2>(aw3, ib, ib, b3, wid, l15, q);
                gemm_f8<4, 2, 4>(aw3, ib, ib, b3, wid, l15, q);
            }
            __syncthreads();

            // head: u + Jacobian cols; waves 0-3: (HF,TF0) ct=wid; waves 4-7: (TF1,TF2)
            {
                f32x4 ha0 = (f32x4){0.f, 0.f, 0.f, 0.f};
                f32x4 ha1 = (f32x4){0.f, 0.f, 0.f, 0.f};
                if (wid < 4) {
                    const int ct = wid;
#pragma unroll
                    for (int s = 0; s < 4; ++s) {
                        int kb = s * 4 + q;
                        bf16x8 af = *(const bf16x8*)(W4p + swb(l15, kb));
                        bf16x8 bA = *(const bf16x8*)(HF + swb(ct * 16 + l15, kb));
                        ha0 = __builtin_amdgcn_mfma_f32_16x16x32_bf16(af, bA, ha0, 0, 0, 0);
                        bf16x8 bB = *(const bf16x8*)(TF0 + swb(ct * 16 + l15, kb));
                        ha1 = __builtin_amdgcn_mfma_f32_16x16x32_bf16(af, bB, ha1, 0, 0, 0);
                    }
                    if (q == 0) {
                        int p = ct * 16 + l15;
#pragma unroll
                        for (int o = 0; o < 3; ++o) {
                            float uv = ha0[o] + b4[o];
                            uls[p * 4 + o] = uv;
                            u_out[(base + p) * 3 + o] = uv;
                        }
#pragma unroll
                        for (int o = 0; o < 3; ++o) gls[p * 12 + o] = ha1[o];
                    }
                } else {
                    const int ct = wid - 4;
#pragma unroll
                    for (int s = 0; s < 4; ++s) {
                        int kb = s * 4 + q;
                        bf16x8 af = *(const bf16x8*)(W4p + swb(l15, kb));
                        bf16x8 bA = *(const bf16x8*)(TF1 + swb(ct * 16 + l15, kb));
                        ha0 = __builtin_amdgcn_mfma_f32_16x16x32_bf16(af, bA, ha0, 0, 0, 0);
                        bf16x8 bB = *(const bf16x8*)(TF2 + swb(ct * 16 + l15, kb));
                        ha1 = __builtin_amdgcn_mfma_f32_16x16x32_bf16(af, bB, ha1, 0, 0, 0);
                    }
                    if (q == 0) {
                        int p = ct * 16 + l15;
#pragma unroll
                        for (int o = 0; o < 3; ++o) gls[p * 12 + 3 + o] = ha0[o];
#pragma unroll
                        for (int o = 0; o < 3; ++o) gls[p * 12 + 6 + o] = ha1[o];
                    }
                }
            }
            __syncthreads();

            // Section A: E_fix + strain energy (wave 0, 64 pts); px0 = coord x of pt tid
            if (tid < 64) {
                int p = tid;
                float xp = xPhys[base + p];
                float xp3 = xp * xp * xp;
                float sc = fminf(fmaxf(px0 * (1.f / LFIX), 0.f), 1.f);
                float ef = 0.f;
                if ((base + p) < nfixv && sc == 0.f) {
                    float u0 = uls[p * 4], u1 = uls[p * 4 + 1], u2 = uls[p * 4 + 2];
                    ef = xp3 * 0.5f * KFIX * (u0 * u0 + u1 * u1 + u2 * u2);
                }
                float g00 = gls[p * 12 + 0], g01 = gls[p * 12 + 1], g02 = gls[p * 12 + 2];
                float g10 = gls[p * 12 + 3], g11 = gls[p * 12 + 4], g12 = gls[p * 12 + 5];
                float g20 = gls[p * 12 + 6], g21 = gls[p * 12 + 7], g22 = gls[p * 12 + 8];
                float e11 = g11, e22 = g00, e33 = g22;
                float e12 = 0.5f * (g01 + g10);
                float e13 = 0.5f * (g21 + g12);
                float e23 = 0.5f * (g20 + g02);
                float tr = e11 + e22 + e33;
                float en = 0.5f * LAMBDA_L * tr * tr +
                           MU_L * (e11 * e11 + e22 * e22 + e33 * e33 +
                                   2.f * (e12 * e12 + e13 * e13 + e23 * e23));
                float exp3 = en * xp3;
                energy_c_out[base + p] = 2.f * exp3;
                float er = exp3;
                ef = wred(ef);
                er = wred(er);
                if (tid == 0) {
                    atomicAdd(acc + 1, ef);
                    atomicAdd(acc + 0, er);
                }
            }
        } else {
            // ================= force block: 64 force points =================
            const int fbase = (bi - ntrb - nmain64) * 64;
            __bf16* HF = pool;
            {
#pragma unroll
                for (int it2 = 0; it2 < 2; ++it2) {
                    const int blk = it2 * 8 + wid, j0 = blk * 8;
                    bf16x8 hv;
#pragma unroll
                    for (int jj = 0; jj < 8; ++jj) {
                        int j = j0 + jj;
                        float z = W1s[3 * HDIM + j] + px0 * W1s[j] + px1 * W1s[HDIM + j] +
                                  px2 * W1s[2 * HDIM + j];
                        hv[jj] = (__bf16)fast_tanh(z);
                    }
                    *(bf16x8*)(HF + swb(lane, blk)) = hv;
                }
            }
            __syncthreads();
            {
                __bf16* ib[1] = {HF};
                gemm_f8<1, 0, 2>(aw2, ib, ib, b2, wid, l15, q);
                gemm_f8<1, 2, 4>(aw2, ib, ib, b2, wid, l15, q);
            }
            __syncthreads();
            {
                __bf16* ib[1] = {HF};
                gemm_f8<1, 0, 2>(aw3, ib, ib, b3, wid, l15, q);
                gemm_f8<1, 2, 4>(aw3, ib, ib, b3, wid, l15, q);
            }
            __syncthreads();
            if (wid < 4) {
                const int ct = wid;
                f32x4 ha = (f32x4){0.f, 0.f, 0.f, 0.f};
#pragma unroll
                for (int s = 0; s < 4; ++s) {
                    int kb = s * 4 + q;
                    bf16x8 af = *(const bf16x8*)(W4p + swb(l15, kb));
                    bf16x8 bf_ = *(const bf16x8*)(HF + swb(ct * 16 + l15, kb));
                    ha = __builtin_amdgcn_mfma_f32_16x16x32_bf16(af, bf_, ha, 0, 0, 0);
                }
                if (q == 0) {
                    int p = ct * 16 + l15;
#pragma unroll
                    for (int o = 0; o < 3; ++o) uls[p * 4 + o] = ha[o] + b4[o];
                }
            }
            __syncthreads();
            if (tid < 64) {
                float fsum = 0.f;
                if (fbase + tid < NF)
                    fsum = uls[tid * 4] * Fv[0] + uls[tid * 4 + 1] * Fv[1] +
                           uls[tid * 4 + 2] * Fv[2];
                fsum = wred(fsum);
                if (tid == 0) atomicAdd(acc + 2, fsum);
            }
        }
    }

    // ---------------- fused finalizer: last block computes the loss ----------------
    __threadfence();
    if (tid == 0) {
        unsigned* done = (unsigned*)(acc + 7);
        unsigned old = atomicAdd(done, 1u);
        if (old == (unsigned)gridDim.x - 1u) {
            __threadfence();
            float es = atomicAdd(acc + 0, 0.f);
            float ef = atomicAdd(acc + 1, 0.f);
            float fl = atomicAdd(acc + 2, 0.f);
            float su = atomicAdd(acc + 3, 0.f);
            float sr = atomicAdd(acc + 4, 0.f);
            float cu = atomicAdd(acc + 5, 0.f);
            float cr = atomicAdd(acc + 6, 0.f);
            float nfix = (float)nfixv;
            float tu = su / fmaxf(cu, 1.f) * nfix;
            float tr = sr / fmaxf(cr, 1.f) * ((float)Ntot - nfix);
            float energy_ans = EMV * (es / (float)Ntot);
            float E_fix = ef * EMV / (float)Ntot;
            float lam = tr / (tu + 1e-12f);
            lam = fminf(fmaxf(lam, 0.001f), 1000.f);
            loss_out[0] = energy_ans - fl + lam * E_fix;
        }
    }
}

extern "C" void kernel_launch(void* const* d_in, const int* in_sizes, int n_in,
                              void* d_out, int out_size, void* d_ws, size_t ws_size,
                              hipStream_t stream) {
    const float* xPhys = (const float*)d_in[0];
    const float* coord = (const float*)d_in[1];
    const float* W1 = (const float*)d_in[2];
    const float* b1 = (const float*)d_in[3];
    const float* W2 = (const float*)d_in[4];
    const float* b2 = (const float*)d_in[5];
    const float* W3 = (const float*)d_in[6];
    const float* b3 = (const float*)d_in[7];
    const float* W4 = (const float*)d_in[8];
    const float* b4 = (const float*)d_in[9];
    const float* fc = (const float*)d_in[10];
    const float* Fv = (const float*)d_in[11];
    const int* nfix = (const int*)d_in[12];

    const int N = in_sizes[0];        // 65536
    const int NF = in_sizes[10] / 3;  // 4096
    float* out = (float*)d_out;
    float* acc = (float*)d_ws;  // [energy, efix, force, su, sr, cnt_u, cnt_r, done]

    const int nm32 = N / 32;
    const int nmain64 = N / 64;
    const int ntrb = nm32 / 8 + 2;  // upper bound on trace tiles
    const int nforce64 = (NF + 63) / 64;
    const int nblocks = ntrb + nmain64 + nforce64;
    (void)hipMemsetAsync(acc, 0, 8 * sizeof(float), stream);
    pinn_all<<<dim3(nblocks), dim3(NTHREADS), 0, stream>>>(
        xPhys, coord, W1, b1, W2, b2, W3, b3, W4, b4, fc, Fv, nfix,
        out + 1, out + 1 + N, acc, nm32, nmain64, ntrb, NF, out, N);
}

// Round 10
// 137.672 us; speedup vs baseline: 2.0327x; 2.0327x over previous
//
#include <hip/hip_runtime.h>
#include <math.h>

typedef __bf16 bf16x8 __attribute__((ext_vector_type(8)));
typedef __bf16 bf16x4 __attribute__((ext_vector_type(4)));
typedef float f32x4 __attribute__((ext_vector_type(4)));

#define HDIM 128
#define NTHREADS 512

#define EMV 0.001f
#define LFIX 0.05f
#define KFIX 100.0f
#define LAMBDA_L 0.5769230769230769f
#define MU_L 0.3846153846153846f

// swizzled bf16 index: 128-wide rows (activations, W4p), 16B granules blk in [0,16)
__device__ __forceinline__ int swb(int r, int blk) {
    return (r << 7) + ((blk ^ (r & 7)) << 3);
}
// swizzled bf16 index: 32-wide rows (trace weight K-chunk), granules g in [0,4)
__device__ __forceinline__ int swb32(int r, int g) {
    return (r << 5) + ((g ^ ((r >> 1) & 3)) << 3);
}

// tanh = 1 - 2/(e^{2x}+1); rcp form saturates correctly at +/-inf -> no clamp
__device__ __forceinline__ float fast_tanh(float x) {
    float e = __expf(2.f * x);
    return 1.f - 2.f * __builtin_amdgcn_rcpf(e + 1.f);
}

__device__ __forceinline__ float wred(float v) {
#pragma unroll
    for (int off = 32; off > 0; off >>= 1) v += __shfl_down(v, off, 64);
    return v;
}

// 8-wave forward GEMM, col-tile range [CT0,CT1). Wave w owns output rows
// [w*16, w*16+16). out[p][n] = sum_j in[p][j]*W[j][n]; aw[s] = W^T K-step frags.
// Epilogue: buf0 -> tanh(acc+bias) -> outb[0]; bufs 1.. -> acc*(1-h^2).
// In-place safe: reads of rows [CT0*16,CT1*16) precede internal barrier; writes
// touch only those rows. CT width kept <=2 to stay spill-free (round-7 lesson).
template <int NB, int CT0, int CT1>
__device__ __forceinline__ void gemm_f8(const bf16x8 (&aw)[4],
                                        __bf16* const* inb, __bf16* const* outb,
                                        const float* __restrict__ bsL,
                                        int wid, int l15, int q) {
    f32x4 acc[NB][CT1 - CT0];
#pragma unroll
    for (int b = 0; b < NB; ++b)
#pragma unroll
        for (int c = 0; c < CT1 - CT0; ++c) acc[b][c] = (f32x4){0.f, 0.f, 0.f, 0.f};

#pragma unroll
    for (int s = 0; s < 4; ++s)
#pragma unroll
        for (int b = 0; b < NB; ++b)
#pragma unroll
            for (int c = CT0; c < CT1; ++c) {
                bf16x8 bfr = *(const bf16x8*)(inb[b] + swb(c * 16 + l15, s * 4 + q));
                acc[b][c - CT0] = __builtin_amdgcn_mfma_f32_16x16x32_bf16(
                    aw[s], bfr, acc[b][c - CT0], 0, 0, 0);
            }
    __syncthreads();  // all reads done before in-place writes
    const int n0 = wid * 16 + q * 4;
    float4 bv = *(const float4*)(bsL + n0);
    float bias4[4] = {bv.x, bv.y, bv.z, bv.w};
#pragma unroll
    for (int c = CT0; c < CT1; ++c) {
        const int p = c * 16 + l15;
        const int widx = swb(p, n0 >> 3) + (n0 & 7);
        bf16x4 hv;
        float fct[4];
#pragma unroll
        for (int i = 0; i < 4; ++i) {
            float h = fast_tanh(acc[0][c - CT0][i] + bias4[i]);
            hv[i] = (__bf16)h;
            fct[i] = 1.f - h * h;
        }
        *(bf16x4*)(outb[0] + widx) = hv;
#pragma unroll
        for (int b = 1; b < NB; ++b) {
            bf16x4 ov;
#pragma unroll
            for (int i = 0; i < 4; ++i) ov[i] = (__bf16)(acc[b][c - CT0][i] * fct[i]);
            *(bf16x4*)(outb[b] + widx) = ov;
        }
    }
}

// 8-wave trace (VJP) GEMM on a 32-pt tile: out[p][j] = sum_k in[p][k]*W[j][k],
// fct from href, in place. Stages W K-chunks (32-wide) into Wst.
template <int NB>
__device__ __forceinline__ void gemm_tr8(const float* __restrict__ Wg, __bf16* Wst,
                                         __bf16* const* bufs,
                                         const __bf16* __restrict__ href,
                                         int wid, int l15, int q, int tid) {
    f32x4 acc[NB][2];
#pragma unroll
    for (int b = 0; b < NB; ++b) {
        acc[b][0] = (f32x4){0.f, 0.f, 0.f, 0.f};
        acc[b][1] = (f32x4){0.f, 0.f, 0.f, 0.f};
    }
#pragma unroll
    for (int c = 0; c < 4; ++c) {
        __syncthreads();  // previous Wst users done
        {
            int j = tid >> 2, k8 = tid & 3;  // 512 granules of 8
            const float4* src = (const float4*)(Wg + j * HDIM + c * 32 + k8 * 8);
            float4 v0 = src[0], v1 = src[1];
            bf16x8 pk = {(__bf16)v0.x, (__bf16)v0.y, (__bf16)v0.z, (__bf16)v0.w,
                         (__bf16)v1.x, (__bf16)v1.y, (__bf16)v1.z, (__bf16)v1.w};
            *(bf16x8*)(Wst + swb32(j, k8)) = pk;
        }
        __syncthreads();
        bf16x8 afr = *(const bf16x8*)(Wst + swb32(wid * 16 + l15, q));
#pragma unroll
        for (int b = 0; b < NB; ++b) {
            bf16x8 b0 = *(const bf16x8*)(bufs[b] + swb(l15, c * 4 + q));
            acc[b][0] = __builtin_amdgcn_mfma_f32_16x16x32_bf16(afr, b0, acc[b][0], 0, 0, 0);
            bf16x8 b1 = *(const bf16x8*)(bufs[b] + swb(16 + l15, c * 4 + q));
            acc[b][1] = __builtin_amdgcn_mfma_f32_16x16x32_bf16(afr, b1, acc[b][1], 0, 0, 0);
        }
    }
    __syncthreads();  // all reads done before in-place writes
    const int n0 = wid * 16 + q * 4;
#pragma unroll
    for (int ct = 0; ct < 2; ++ct) {
        const int p = ct * 16 + l15;
        const int widx = swb(p, n0 >> 3) + (n0 & 7);
        bf16x4 hv = *(const bf16x4*)(href + widx);
        float fct[4];
#pragma unroll
        for (int i = 0; i < 4; ++i) {
            float h = (float)hv[i];
            fct[i] = 1.f - h * h;
        }
#pragma unroll
        for (int b = 0; b < NB; ++b) {
            bf16x4 ov;
#pragma unroll
            for (int i = 0; i < 4; ++i) ov[i] = (__bf16)(acc[b][ct][i] * fct[i]);
            *(bf16x4*)(bufs[b] + widx) = ov;
        }
    }
}

// 512-thread sum-of-squares of 3 32-pt buffers: npart[(buf*16+cc)*32+p]
__device__ __forceinline__ void dnorms8(const __bf16* a, const __bf16* b, const __bf16* c2,
                                        float* npart, int tid) {
    int p = tid & 31, cc = tid >> 5;  // cc in [0,16)
    bf16x8 v0 = *(const bf16x8*)(a + swb(p, cc));
    bf16x8 v1 = *(const bf16x8*)(b + swb(p, cc));
    bf16x8 v2 = *(const bf16x8*)(c2 + swb(p, cc));
    float s0 = 0.f, s1 = 0.f, s2 = 0.f;
#pragma unroll
    for (int e = 0; e < 8; ++e) {
        float f0 = (float)v0[e], f1 = (float)v1[e], f2 = (float)v2[e];
        s0 += f0 * f0;
        s1 += f1 * f1;
        s2 += f2 * f2;
    }
    npart[(0 + cc) * 32 + p] = s0;
    npart[(16 + cc) * 32 + p] = s1;
    npart[(32 + cc) * 32 + p] = s2;
}

__device__ __forceinline__ float sum16(const float* npart, int buf, int p) {
    float d = 0.f;
#pragma unroll
    for (int i = 0; i < 16; ++i) d += npart[(buf * 16 + i) * 32 + p];
    return d;
}
__device__ __forceinline__ float sum48(const float* npart, int p) {
    float d = 0.f;
#pragma unroll
    for (int i = 0; i < 48; ++i) d += npart[i * 32 + p];
    return d;
}

__global__ void __launch_bounds__(NTHREADS, 4) pinn_all(
    const float* __restrict__ xPhys, const float* __restrict__ coord,
    const float* __restrict__ W1, const float* __restrict__ b1,
    const float* __restrict__ W2, const float* __restrict__ b2,
    const float* __restrict__ W3, const float* __restrict__ b3,
    const float* __restrict__ W4, const float* __restrict__ b4,
    const float* __restrict__ fc, const float* __restrict__ Fv,
    const int* __restrict__ nfixp,
    float* __restrict__ energy_c_out, float* __restrict__ u_out,
    float* __restrict__ acc, int nm32, int nmain64, int ntrb, int NF) {
    // 64KB pool: fwd view = 4 x (64x128) bf16; trace view = 6 x (32x128) + Wstage + npart
    __shared__ __align__(16) __bf16 pool[32768];
    __shared__ __align__(16) __bf16 W4p[16 * HDIM];  // 4KB padded W4^T
    __shared__ __align__(16) float W1s[4 * HDIM];    // w0,w1,w2,b1
    __shared__ __align__(16) float W4ts[3 * HDIM];
    __shared__ __align__(16) float gls[64 * 12];
    __shared__ __align__(16) float uls[64 * 4];
    __shared__ float nh1s[32], nh2s[32], nh3s[32];
    // total ~75.9KB -> 2 blocks/CU, 16 waves/CU

    const int tid = threadIdx.x;
    const int lane = tid & 63, wid = tid >> 6, l15 = lane & 15, q = lane >> 4;
    const int bi = blockIdx.x;
    const int nfixv = nfixp[0];

    // ---- trace-block tile enumeration (same sampled 32-pt sets as verified kernel) ----
    int ttile = -1;
    if (bi < ntrb) {
        const int nfull = nfixv >> 5;          // fully-fix 32-pt tiles
        const int cm = (nfixv & 31) ? 1 : 0;   // mixed tile exists?
        const int c1 = (nfull + 7) >> 3;       // fix trace tiles: t = 8i < nfull
        int t;
        if (bi < c1) {
            t = bi << 3;
        } else if (cm && bi == c1) {
            t = nfull;  // mixed tile always traced
        } else {
            const int rr0 = nfull + cm;
            const int f0 = rr0 + ((8 - (rr0 & 15) + 16) & 15);  // first t>=rr0, t%16==8
            t = f0 + ((bi - c1 - cm) << 4);
        }
        if (t >= nm32) return;  // idle trace block
        ttile = t;
    }

    // ---- coord prefetch (hides HBM/L2 latency under the staging prologue) ----
    float px0, px1, px2;
    if (bi < ntrb) {
        const float* cp = coord + (ttile * 32 + (lane & 31)) * 3;
        px0 = cp[0]; px1 = cp[1]; px2 = cp[2];
    } else if (bi < ntrb + nmain64) {
        const float* cp = coord + ((bi - ntrb) * 64 + lane) * 3;
        px0 = cp[0]; px1 = cp[1]; px2 = cp[2];
    } else {
        int pp = (bi - ntrb - nmain64) * 64 + lane;
        if (pp >= NF) pp = NF - 1;
        const float* cp = fc + pp * 3;
        px0 = cp[0]; px1 = cp[1]; px2 = cp[2];
    }

    // ---------------- block-invariant staging ----------------
    for (int i = tid; i < 3 * HDIM; i += NTHREADS) W1s[i] = W1[i];
    if (tid < HDIM) W1s[3 * HDIM + tid] = b1[tid];
    if (tid < 3 * HDIM) W4ts[tid] = W4[(tid & 127) * 3 + (tid >> 7)];
    if (tid < 256) {  // W4p (padded W4^T)
        int o = tid >> 4, blk = tid & 15, j0 = blk * 8;
        bf16x8 pk;
#pragma unroll
        for (int e = 0; e < 8; ++e) pk[e] = (__bf16)((o < 3) ? W4[(j0 + e) * 3 + o] : 0.f);
        *(bf16x8*)(W4p + swb(o, blk)) = pk;
    }
    // register-resident W2/W3 fragments: wave w owns n-rows [w*16, w*16+16)
    bf16x8 aw2[4], aw3[4];
#pragma unroll
    for (int s = 0; s < 4; ++s) {
        const int kb = s * 32 + q * 8;
        const int n = wid * 16 + l15;
        bf16x8 v2, v3;
#pragma unroll
        for (int e = 0; e < 8; ++e) {
            v2[e] = (__bf16)W2[(kb + e) * HDIM + n];
            v3[e] = (__bf16)W3[(kb + e) * HDIM + n];
        }
        aw2[s] = v2;
        aw3[s] = v3;
    }
    __syncthreads();

    if (bi < ntrb) {
        // ================= trace block: one sampled 32-pt tile =================
        const int base = ttile * 32;
        __bf16* H1 = pool;
        __bf16* H2 = pool + 4096;
        __bf16* H3 = pool + 8192;
        __bf16* T0 = pool + 12288;
        __bf16* T1 = pool + 16384;
        __bf16* T2 = pool + 20480;
        __bf16* WST = pool + 24576;             // 8KB
        float* npart = (float*)(pool + 28672);  // 1536 floats (6KB)

        {  // layer 1 + tangent seeds: point-per-lane, granule-per-wave
            const int p = lane & 31, sub = lane >> 5;
            const int blk = wid * 2 + sub, j0 = blk * 8;
            bf16x8 hv, t0v, t1v, t2v;
#pragma unroll
            for (int jj = 0; jj < 8; ++jj) {
                int j = j0 + jj;
                float w0 = W1s[j], w1 = W1s[HDIM + j], w2 = W1s[2 * HDIM + j];
                float z = W1s[3 * HDIM + j] + px0 * w0 + px1 * w1 + px2 * w2;
                float h = fast_tanh(z);
                float fct = 1.f - h * h;
                hv[jj] = (__bf16)h;
                t0v[jj] = (__bf16)(fct * w0);
                t1v[jj] = (__bf16)(fct * w1);
                t2v[jj] = (__bf16)(fct * w2);
            }
            int wi = swb(p, blk);
            *(bf16x8*)(H1 + wi) = hv;
            *(bf16x8*)(T0 + wi) = t0v;
            *(bf16x8*)(T1 + wi) = t1v;
            *(bf16x8*)(T2 + wi) = t2v;
        }
        __syncthreads();
        {
            __bf16* ib[4] = {H1, T0, T1, T2};
            __bf16* ob[4] = {H2, T0, T1, T2};
            gemm_f8<4, 0, 2>(aw2, ib, ob, b2, wid, l15, q);
        }
        __syncthreads();
        {
            __bf16* ib[4] = {H2, T0, T1, T2};
            __bf16* ob[4] = {H3, T0, T1, T2};
            gemm_f8<4, 0, 2>(aw3, ib, ob, b3, wid, l15, q);
        }
        __syncthreads();

        dnorms8(H1, H2, H3, npart, tid);
        __syncthreads();
        if (tid < 32) {
            nh1s[tid] = sum16(npart, 0, tid);
            nh2s[tid] = sum16(npart, 1, tid);
            nh3s[tid] = sum16(npart, 2, tid);
        }
        __syncthreads();
        {  // delta3 seeds into T0..T2 (broadcast indexing)
            const int p = lane & 31, sub = lane >> 5;
            const int blk = wid * 2 + sub, j0 = blk * 8;
            bf16x8 h3v = *(const bf16x8*)(H3 + swb(p, blk));
            bf16x8 d0, d1, d2;
#pragma unroll
            for (int e = 0; e < 8; ++e) {
                float h = (float)h3v[e];
                float fct = 1.f - h * h;
                d0[e] = (__bf16)(fct * W4ts[j0 + e]);
                d1[e] = (__bf16)(fct * W4ts[HDIM + j0 + e]);
                d2[e] = (__bf16)(fct * W4ts[2 * HDIM + j0 + e]);
            }
            int wi = swb(p, blk);
            *(bf16x8*)(T0 + wi) = d0;
            *(bf16x8*)(T1 + wi) = d1;
            *(bf16x8*)(T2 + wi) = d2;
        }
        __syncthreads();
        float s_acc = 0.f;
        dnorms8(T0, T1, T2, npart, tid);
        __syncthreads();
        if (tid < 32) s_acc = sum48(npart, tid) * (1.f + nh2s[tid]);
        {
            __bf16* ib[3] = {T0, T1, T2};
            gemm_tr8<3>(W3, WST, ib, H2, wid, l15, q, tid);  // delta2
        }
        __syncthreads();
        dnorms8(T0, T1, T2, npart, tid);
        __syncthreads();
        if (tid < 32) s_acc += sum48(npart, tid) * (1.f + nh1s[tid]);
        {
            __bf16* ib[3] = {T0, T1, T2};
            gemm_tr8<3>(W2, WST, ib, H1, wid, l15, q, tid);  // delta1
        }
        __syncthreads();
        dnorms8(T0, T1, T2, npart, tid);
        __syncthreads();
        if (tid < 64) {
            float su = 0.f, sr = 0.f, cu = 0.f, cr = 0.f;
            if (tid < 32) {
                int p = tid;
                float nx = px0 * px0 + px1 * px1 + px2 * px2;
                float s = s_acc + sum48(npart, p) * (1.f + nx) + 3.f * (nh3s[p] + 1.f);
                bool uu = (base + p) < nfixv;
                su = uu ? s : 0.f;
                sr = uu ? 0.f : s;
                cu = uu ? 1.f : 0.f;
                cr = uu ? 0.f : 1.f;
            }
            su = wred(su);
            sr = wred(sr);
            cu = wred(cu);
            cr = wred(cr);
            if (tid == 0) {
                atomicAdd(acc + 3, su);
                atomicAdd(acc + 4, sr);
                atomicAdd(acc + 5, cu);
                atomicAdd(acc + 6, cr);
            }
        }
    } else if (bi < ntrb + nmain64) {
        // ================= forward block: 64 coord points (no trace) =================
        const int base = (bi - ntrb) * 64;
        __bf16* HF = pool;  // in-place h1 -> h2 -> h3
        __bf16* TF0 = pool + 8192;
        __bf16* TF1 = pool + 16384;
        __bf16* TF2 = pool + 24576;

        {  // layer 1 + tangent seeds: point-per-lane, granule-per-wave
            const int p = lane;
#pragma unroll
            for (int it2 = 0; it2 < 2; ++it2) {
                const int blk = it2 * 8 + wid, j0 = blk * 8;
                bf16x8 hv, t0v, t1v, t2v;
#pragma unroll
                for (int jj = 0; jj < 8; ++jj) {
                    int j = j0 + jj;
                    float w0 = W1s[j], w1 = W1s[HDIM + j], w2 = W1s[2 * HDIM + j];
                    float z = W1s[3 * HDIM + j] + px0 * w0 + px1 * w1 + px2 * w2;
                    float h = fast_tanh(z);
                    float fct = 1.f - h * h;
                    hv[jj] = (__bf16)h;
                    t0v[jj] = (__bf16)(fct * w0);
                    t1v[jj] = (__bf16)(fct * w1);
                    t2v[jj] = (__bf16)(fct * w2);
                }
                int wi = swb(p, blk);
                *(bf16x8*)(HF + wi) = hv;
                *(bf16x8*)(TF0 + wi) = t0v;
                *(bf16x8*)(TF1 + wi) = t1v;
                *(bf16x8*)(TF2 + wi) = t2v;
            }
        }
        __syncthreads();
        {  // layer 2 (two col-tile passes, disjoint rows; each has internal barrier)
            __bf16* ib[4] = {HF, TF0, TF1, TF2};
            gemm_f8<4, 0, 2>(aw2, ib, ib, b2, wid, l15, q);
            gemm_f8<4, 2, 4>(aw2, ib, ib, b2, wid, l15, q);
        }
        __syncthreads();
        {  // layer 3
            __bf16* ib[4] = {HF, TF0, TF1, TF2};
            gemm_f8<4, 0, 2>(aw3, ib, ib, b3, wid, l15, q);
            gemm_f8<4, 2, 4>(aw3, ib, ib, b3, wid, l15, q);
        }
        __syncthreads();

        // head: u + Jacobian cols; waves 0-3: (HF,TF0) ct=wid; waves 4-7: (TF1,TF2)
        {
            f32x4 ha0 = (f32x4){0.f, 0.f, 0.f, 0.f};
            f32x4 ha1 = (f32x4){0.f, 0.f, 0.f, 0.f};
            if (wid < 4) {
                const int ct = wid;
#pragma unroll
                for (int s = 0; s < 4; ++s) {
                    int kb = s * 4 + q;
                    bf16x8 af = *(const bf16x8*)(W4p + swb(l15, kb));
                    bf16x8 bA = *(const bf16x8*)(HF + swb(ct * 16 + l15, kb));
                    ha0 = __builtin_amdgcn_mfma_f32_16x16x32_bf16(af, bA, ha0, 0, 0, 0);
                    bf16x8 bB = *(const bf16x8*)(TF0 + swb(ct * 16 + l15, kb));
                    ha1 = __builtin_amdgcn_mfma_f32_16x16x32_bf16(af, bB, ha1, 0, 0, 0);
                }
                if (q == 0) {
                    int p = ct * 16 + l15;
#pragma unroll
                    for (int o = 0; o < 3; ++o) {
                        float uv = ha0[o] + b4[o];
                        uls[p * 4 + o] = uv;
                        u_out[(base + p) * 3 + o] = uv;
                    }
#pragma unroll
                    for (int o = 0; o < 3; ++o) gls[p * 12 + o] = ha1[o];
                }
            } else {
                const int ct = wid - 4;
#pragma unroll
                for (int s = 0; s < 4; ++s) {
                    int kb = s * 4 + q;
                    bf16x8 af = *(const bf16x8*)(W4p + swb(l15, kb));
                    bf16x8 bA = *(const bf16x8*)(TF1 + swb(ct * 16 + l15, kb));
                    ha0 = __builtin_amdgcn_mfma_f32_16x16x32_bf16(af, bA, ha0, 0, 0, 0);
                    bf16x8 bB = *(const bf16x8*)(TF2 + swb(ct * 16 + l15, kb));
                    ha1 = __builtin_amdgcn_mfma_f32_16x16x32_bf16(af, bB, ha1, 0, 0, 0);
                }
                if (q == 0) {
                    int p = ct * 16 + l15;
#pragma unroll
                    for (int o = 0; o < 3; ++o) gls[p * 12 + 3 + o] = ha0[o];
#pragma unroll
                    for (int o = 0; o < 3; ++o) gls[p * 12 + 6 + o] = ha1[o];
                }
            }
        }
        __syncthreads();

        // Section A: E_fix + strain energy (wave 0, 64 pts); px0 = coord x of pt tid
        if (tid < 64) {
            int p = tid;
            float xp = xPhys[base + p];
            float xp3 = xp * xp * xp;
            float sc = fminf(fmaxf(px0 * (1.f / LFIX), 0.f), 1.f);
            float ef = 0.f;
            if ((base + p) < nfixv && sc == 0.f) {
                float u0 = uls[p * 4], u1 = uls[p * 4 + 1], u2 = uls[p * 4 + 2];
                ef = xp3 * 0.5f * KFIX * (u0 * u0 + u1 * u1 + u2 * u2);
            }
            float g00 = gls[p * 12 + 0], g01 = gls[p * 12 + 1], g02 = gls[p * 12 + 2];
            float g10 = gls[p * 12 + 3], g11 = gls[p * 12 + 4], g12 = gls[p * 12 + 5];
            float g20 = gls[p * 12 + 6], g21 = gls[p * 12 + 7], g22 = gls[p * 12 + 8];
            float e11 = g11, e22 = g00, e33 = g22;
            float e12 = 0.5f * (g01 + g10);
            float e13 = 0.5f * (g21 + g12);
            float e23 = 0.5f * (g20 + g02);
            float tr = e11 + e22 + e33;
            float en = 0.5f * LAMBDA_L * tr * tr +
                       MU_L * (e11 * e11 + e22 * e22 + e33 * e33 +
                               2.f * (e12 * e12 + e13 * e13 + e23 * e23));
            float exp3 = en * xp3;
            energy_c_out[base + p] = 2.f * exp3;
            float er = exp3;
            ef = wred(ef);
            er = wred(er);
            if (tid == 0) {
                atomicAdd(acc + 1, ef);
                atomicAdd(acc + 0, er);
            }
        }
    } else {
        // ================= force block: 64 force points =================
        const int fbase = (bi - ntrb - nmain64) * 64;
        __bf16* HF = pool;
        {
#pragma unroll
            for (int it2 = 0; it2 < 2; ++it2) {
                const int blk = it2 * 8 + wid, j0 = blk * 8;
                bf16x8 hv;
#pragma unroll
                for (int jj = 0; jj < 8; ++jj) {
                    int j = j0 + jj;
                    float z = W1s[3 * HDIM + j] + px0 * W1s[j] + px1 * W1s[HDIM + j] +
                              px2 * W1s[2 * HDIM + j];
                    hv[jj] = (__bf16)fast_tanh(z);
                }
                *(bf16x8*)(HF + swb(lane, blk)) = hv;
            }
        }
        __syncthreads();
        {
            __bf16* ib[1] = {HF};
            gemm_f8<1, 0, 2>(aw2, ib, ib, b2, wid, l15, q);
            gemm_f8<1, 2, 4>(aw2, ib, ib, b2, wid, l15, q);
        }
        __syncthreads();
        {
            __bf16* ib[1] = {HF};
            gemm_f8<1, 0, 2>(aw3, ib, ib, b3, wid, l15, q);
            gemm_f8<1, 2, 4>(aw3, ib, ib, b3, wid, l15, q);
        }
        __syncthreads();
        if (wid < 4) {
            const int ct = wid;
            f32x4 ha = (f32x4){0.f, 0.f, 0.f, 0.f};
#pragma unroll
            for (int s = 0; s < 4; ++s) {
                int kb = s * 4 + q;
                bf16x8 af = *(const bf16x8*)(W4p + swb(l15, kb));
                bf16x8 bf_ = *(const bf16x8*)(HF + swb(ct * 16 + l15, kb));
                ha = __builtin_amdgcn_mfma_f32_16x16x32_bf16(af, bf_, ha, 0, 0, 0);
            }
            if (q == 0) {
                int p = ct * 16 + l15;
#pragma unroll
                for (int o = 0; o < 3; ++o) uls[p * 4 + o] = ha[o] + b4[o];
            }
        }
        __syncthreads();
        if (tid < 64) {
            float fsum = 0.f;
            if (fbase + tid < NF)
                fsum = uls[tid * 4] * Fv[0] + uls[tid * 4 + 1] * Fv[1] +
                       uls[tid * 4 + 2] * Fv[2];
            fsum = wred(fsum);
            if (tid == 0) atomicAdd(acc + 2, fsum);
        }
    }
}

__global__ void pinn_final(const float* __restrict__ acc, float* __restrict__ out,
                           int Ntot, const int* __restrict__ nfixp) {
    float es = acc[0], ef = acc[1], fl = acc[2];
    float su = acc[3], sr = acc[4], cu = acc[5], cr = acc[6];
    float nfix = (float)nfixp[0];
    float tu = su / fmaxf(cu, 1.f) * nfix;
    float tr = sr / fmaxf(cr, 1.f) * ((float)Ntot - nfix);
    float energy_ans = EMV * (es / (float)Ntot);
    float E_fix = ef * EMV / (float)Ntot;
    float lam = tr / (tu + 1e-12f);
    lam = fminf(fmaxf(lam, 0.001f), 1000.f);
    out[0] = energy_ans - fl + lam * E_fix;
}

extern "C" void kernel_launch(void* const* d_in, const int* in_sizes, int n_in,
                              void* d_out, int out_size, void* d_ws, size_t ws_size,
                              hipStream_t stream) {
    const float* xPhys = (const float*)d_in[0];
    const float* coord = (const float*)d_in[1];
    const float* W1 = (const float*)d_in[2];
    const float* b1 = (const float*)d_in[3];
    const float* W2 = (const float*)d_in[4];
    const float* b2 = (const float*)d_in[5];
    const float* W3 = (const float*)d_in[6];
    const float* b3 = (const float*)d_in[7];
    const float* W4 = (const float*)d_in[8];
    const float* b4 = (const float*)d_in[9];
    const float* fc = (const float*)d_in[10];
    const float* Fv = (const float*)d_in[11];
    const int* nfix = (const int*)d_in[12];

    const int N = in_sizes[0];        // 65536
    const int NF = in_sizes[10] / 3;  // 4096
    float* out = (float*)d_out;
    float* acc = (float*)d_ws;  // [energy, efix, force, su, sr, cnt_u, cnt_r]

    const int nm32 = N / 32;
    const int nmain64 = N / 64;
    const int ntrb = nm32 / 8 + 2;  // upper bound on trace tiles
    const int nforce64 = (NF + 63) / 64;
    const int nblocks = ntrb + nmain64 + nforce64;
    (void)hipMemsetAsync(acc, 0, 8 * sizeof(float), stream);
    pinn_all<<<dim3(nblocks), dim3(NTHREADS), 0, stream>>>(
        xPhys, coord, W1, b1, W2, b2, W3, b3, W4, b4, fc, Fv, nfix,
        out + 1, out + 1 + N, acc, nm32, nmain64, ntrb, NF);
    pinn_final<<<dim3(1), dim3(1), 0, stream>>>(acc, out, N, nfix);
}